// Round 4
// baseline (2651.191 us; speedup 1.0000x reference)
//
#include <hip/hip_runtime.h>
#include <math.h>

#define BB 512
#define LL 128
#define FD 8
#define HD 512
#define EPSV 1e-5f

typedef __attribute__((ext_vector_type(8))) __bf16 bf16x8;
typedef __attribute__((ext_vector_type(4))) float floatx4;

__device__ __forceinline__ float silu_f(float x){ return x / (1.0f + expf(-x)); }
__device__ __forceinline__ float softplus_f(float x){ return (x > 20.0f) ? x : log1pf(expf(x)); }

__device__ __forceinline__ unsigned short f2bf(float x){
    union { float f; unsigned u; } v; v.f = x;
    unsigned r = v.u + 0x7fffu + ((v.u >> 16) & 1u);   // RNE
    return (unsigned short)(r >> 16);
}
__device__ __forceinline__ float bf2f(unsigned short h){
    union { unsigned u; float f; } v; v.u = ((unsigned)h) << 16; return v.f;
}
__device__ __forceinline__ void split_bf(float x, unsigned short* hi, unsigned short* lo){
    unsigned short h = f2bf(x);
    *hi = h;
    *lo = f2bf(x - bf2f(h));
}

// ---------------- embed: h = x @ w0 + b0 -> hi/lo bf16 only ----------------
__global__ __launch_bounds__(256) void k_embed(const float* __restrict__ x,
    const float* __restrict__ w0, const float* __restrict__ b0,
    unsigned short* __restrict__ hhi, unsigned short* __restrict__ hlo)
{
    int idx = blockIdx.x*256 + threadIdx.x;      // over rows*HD
    int c = idx & (HD-1);
    int row = idx >> 9;
    const float* xr = x + (size_t)row*FD;
    float acc = b0[c];
    #pragma unroll
    for (int f=0; f<FD; ++f) acc = fmaf(xr[f], w0[f*HD + c], acc);
    unsigned short hi, lo; split_bf(acc, &hi, &lo);
    hhi[idx] = hi; hlo[idx] = lo;
}

// ---------------- weight transpose + hi/lo split: W[K][N] fp32 -> Wt[N][K] bf16 ----------------
__global__ __launch_bounds__(256) void k_cvt_wt(const float* __restrict__ W,
    unsigned short* __restrict__ Thi, unsigned short* __restrict__ Tlo, int N, int kbits)
{
    int idx = blockIdx.x*256 + threadIdx.x;      // over N*K, k fastest
    int K = 1 << kbits;
    int n = idx >> kbits, k = idx & (K-1);
    float v = W[(size_t)k*N + n];
    unsigned short hi, lo; split_bf(v, &hi, &lo);
    Thi[idx] = hi; Tlo[idx] = lo;
}

// ---------------- xp_w transpose: [512][16] -> [16][512] fp32 ----------------
__global__ __launch_bounds__(256) void k_tr16(const float* __restrict__ W,
    float* __restrict__ Wt)
{
    int idx = blockIdx.x*256 + threadIdx.x;      // over 16*512
    int j = idx >> 9, c = idx & 511;
    Wt[idx] = W[c*16 + j];
}

// ---------------- split-bf16 MFMA GEMM, 128x128 tile, 4 waves, 16x16x32 ----------------
// C = A(MxK) @ Wt(NxK)^T, acc fp32 via hi*hi + hi*lo + lo*hi.
// MODE 0 (in_proj, KDIM=512, N=1024): col<512 -> silu -> oA[row][512+col] (bf16 hi/lo)
//                                     col>=512 -> outF[row][col-512] fp32 (xi)
// MODE 1 (out_proj, KDIM=1024, N=512): outF = v + bias + (rhi+rlo) (fp32, pre-LN)
template<int KDIM, int MODE>
__global__ __launch_bounds__(256) void k_mgemm(
    const unsigned short* __restrict__ Ahi, const unsigned short* __restrict__ Alo,
    const unsigned short* __restrict__ Bhi, const unsigned short* __restrict__ Blo,
    const float* __restrict__ bias,
    const unsigned short* __restrict__ rhi, const unsigned short* __restrict__ rlo,
    float* __restrict__ outF,
    unsigned short* __restrict__ oAhi, unsigned short* __restrict__ oAlo)
{
    __shared__ unsigned short lds[4 * 4096];     // 4 tiles of 128x32 bf16 (8 KB each)
    const int tid  = threadIdx.x;
    const int wv   = tid >> 6, lane = tid & 63;
    const int quad = lane >> 4, l16 = lane & 15;
    const size_t mBase = (size_t)blockIdx.y * 128;
    const int nBase = blockIdx.x * 128;
    const int wm = (wv & 1) * 64, wn = (wv >> 1) * 64;

    floatx4 acc[4][4] = {};

    const int rowIn = lane >> 2;                 // 0..15
    const int kofs  = (lane & 3) * 8;            // bf16 units within 32-wide k tile
    const unsigned short* gsrc[4];
    gsrc[0] = Ahi + mBase * KDIM;
    gsrc[1] = Alo + mBase * KDIM;
    gsrc[2] = Bhi + (size_t)nBase * KDIM;
    gsrc[3] = Blo + (size_t)nBase * KDIM;

    for (int k0 = 0; k0 < KDIM; k0 += 32) {
        #pragma unroll
        for (int b = 0; b < 4; ++b) {
            #pragma unroll
            for (int r = 0; r < 2; ++r) {
                int row = r * 64 + wv * 16 + rowIn;
                const unsigned short* g = gsrc[b] + (size_t)row * KDIM + k0 + kofs;
                unsigned short* l = &lds[b * 4096 + r * 2048 + wv * 512]; // +lane*16B implicit
                __builtin_amdgcn_global_load_lds(
                    (const __attribute__((address_space(1))) void*)g,
                    (__attribute__((address_space(3))) void*)l, 16, 0, 0);
            }
        }
        __syncthreads();
        bf16x8 ah[4], al[4], bh[4], bl[4];
        #pragma unroll
        for (int i = 0; i < 4; ++i) {
            int am = wm + 16*i + l16;
            ah[i] = *(const bf16x8*)&lds[0*4096 + am*32 + quad*8];
            al[i] = *(const bf16x8*)&lds[1*4096 + am*32 + quad*8];
            int bn = wn + 16*i + l16;
            bh[i] = *(const bf16x8*)&lds[2*4096 + bn*32 + quad*8];
            bl[i] = *(const bf16x8*)&lds[3*4096 + bn*32 + quad*8];
        }
        #pragma unroll
        for (int i = 0; i < 4; ++i)
            #pragma unroll
            for (int j = 0; j < 4; ++j) {
                acc[i][j] = __builtin_amdgcn_mfma_f32_16x16x32_bf16(ah[i], bh[j], acc[i][j], 0, 0, 0);
                acc[i][j] = __builtin_amdgcn_mfma_f32_16x16x32_bf16(ah[i], bl[j], acc[i][j], 0, 0, 0);
                acc[i][j] = __builtin_amdgcn_mfma_f32_16x16x32_bf16(al[i], bh[j], acc[i][j], 0, 0, 0);
            }
        __syncthreads();
    }

    // epilogue: D[row=(quad*4+r) within 16, col=l16 within 16]
    #pragma unroll
    for (int i = 0; i < 4; ++i) {
        #pragma unroll
        for (int r = 0; r < 4; ++r) {
            size_t row = mBase + wm + 16*i + quad*4 + r;
            #pragma unroll
            for (int j = 0; j < 4; ++j) {
                int col = nBase + wn + 16*j + l16;
                float v = acc[i][j][r] + bias[col];
                if (MODE == 0) {
                    if (col < 512) {
                        float s = silu_f(v);
                        unsigned short hi, lo; split_bf(s, &hi, &lo);
                        oAhi[row*1024 + 512 + col] = hi;
                        oAlo[row*1024 + 512 + col] = lo;
                    } else {
                        outF[row*512 + (col - 512)] = v;
                    }
                } else {
                    size_t idx = row*512 + col;
                    v += bf2f(rhi[idx]) + bf2f(rlo[idx]);
                    outF[idx] = v;
                }
            }
        }
    }
}

// ---------------- fused conv3+silu + dt bottleneck + multiply + split ----------------
// one block = 16 consecutive l-positions of one batch (LL=128 -> 8 tiles/batch)
__global__ __launch_bounds__(256) void k_cdt(const float* __restrict__ xb,
    const float* __restrict__ cw, const float* __restrict__ cb,
    const float* __restrict__ xpwT,   // [16][512] fp32 (transposed xp_w)
    const float* __restrict__ xp_b,
    const float* __restrict__ dt_w, const float* __restrict__ dt_b,
    unsigned short* __restrict__ oAhi, unsigned short* __restrict__ oAlo)
{
    __shared__ float xc_s[16*516];    // padded stride 516 to dodge b128 bank conflicts
    __shared__ float T_s[16*17];
    const int tid = threadIdx.x;
    const int tile = blockIdx.x;
    const int l0 = (tile & 7) * 16;
    const size_t rowBase = (size_t)tile * 16;

    // conv + silu -> xc_s (rolling 3-tap per column)
    #pragma unroll
    for (int p = 0; p < 2; ++p) {
        int c = p*256 + tid;
        float w0c = cw[c*3+0], w1c = cw[c*3+1], w2c = cw[c*3+2], bc = cb[c];
        const float* col = xb + rowBase*512 + c;
        float xm = (l0 > 0) ? col[-512] : 0.0f;
        float x0 = col[0];
        #pragma unroll
        for (int r = 0; r < 16; ++r) {
            float xp = (l0 + r < 127) ? col[(r+1)*512] : 0.0f;
            float v = bc;
            v = fmaf(xm, w0c, v);
            v = fmaf(x0, w1c, v);
            v = fmaf(xp, w2c, v);
            xc_s[r*516 + c] = silu_f(v);
            xm = x0; x0 = xp;
        }
    }
    __syncthreads();

    // T[r][j] = sum_c xc[r][c] * xp_w[c][j] + xp_b[j]   (thread r=tid>>4, j=tid&15)
    {
        int r = tid >> 4, j = tid & 15;
        const float* wj = xpwT + j*512;
        float a0=0.f, a1=0.f, a2=0.f, a3=0.f;
        #pragma unroll 4
        for (int c4 = 0; c4 < 128; ++c4) {
            float4 xv = *(const float4*)&xc_s[r*516 + c4*4];
            float4 wv = *(const float4*)(wj + c4*4);
            a0 = fmaf(xv.x, wv.x, a0);
            a1 = fmaf(xv.y, wv.y, a1);
            a2 = fmaf(xv.z, wv.z, a2);
            a3 = fmaf(xv.w, wv.w, a3);
        }
        T_s[r*17 + j] = (a0+a1)+(a2+a3) + xp_b[j];
    }
    __syncthreads();

    // dt = softplus(T @ dt_w + dt_b); out = xc * dt -> bf16 hi/lo
    #pragma unroll
    for (int p = 0; p < 2; ++p) {
        int c = p*256 + tid;
        float wv[16];
        #pragma unroll
        for (int j = 0; j < 16; ++j) wv[j] = dt_w[j*512 + c];
        float bc = dt_b[c];
        #pragma unroll
        for (int r = 0; r < 16; ++r) {
            float d = bc;
            #pragma unroll
            for (int j = 0; j < 16; ++j) d = fmaf(T_s[r*17 + j], wv[j], d);
            float v = xc_s[r*516 + c] * softplus_f(d);
            unsigned short hi, lo; split_bf(v, &hi, &lo);
            size_t ob = (rowBase + r)*1024 + c;
            oAhi[ob] = hi; oAlo[ob] = lo;
        }
    }
}

// ---------------- layernorm over last dim (512); emit hi/lo bf16 only ----------------
__global__ __launch_bounds__(256) void k_ln(const float* __restrict__ in,
    const float* __restrict__ g, const float* __restrict__ b,
    unsigned short* __restrict__ ohi, unsigned short* __restrict__ olo)
{
    __shared__ float s1[4], s2[4], sm[2];
    int row = blockIdx.x, tid = threadIdx.x;
    size_t base = (size_t)row * HD;
    float x0 = in[base + tid], x1 = in[base + tid + 256];
    float s = x0 + x1, q = x0*x0 + x1*x1;
    for (int off = 32; off; off >>= 1) { s += __shfl_down(s, off); q += __shfl_down(q, off); }
    int lane = tid & 63, wid = tid >> 6;
    if (!lane) { s1[wid] = s; s2[wid] = q; }
    __syncthreads();
    if (!tid) {
        float ts = s1[0]+s1[1]+s1[2]+s1[3];
        float tq = s2[0]+s2[1]+s2[2]+s2[3];
        float mu = ts / (float)HD;
        float var = tq / (float)HD - mu*mu;
        sm[0] = mu; sm[1] = rsqrtf(var + EPSV);
    }
    __syncthreads();
    float mu = sm[0], rs = sm[1];
    float o0 = (x0 - mu) * rs * g[tid]       + b[tid];
    float o1 = (x1 - mu) * rs * g[tid + 256] + b[tid + 256];
    unsigned short hi, lo;
    split_bf(o0, &hi, &lo); ohi[base + tid] = hi;       olo[base + tid] = lo;
    split_bf(o1, &hi, &lo); ohi[base + tid + 256] = hi; olo[base + tid + 256] = lo;
}

// ---------------- head: reg/dec, gate softmax+argmax, expert select ----------------
__global__ __launch_bounds__(256) void k_head(
    const unsigned short* __restrict__ hhi, const unsigned short* __restrict__ hlo,
    const float* __restrict__ gumbel, const float* __restrict__ gate_w,
    const float* __restrict__ gate_b, const float* __restrict__ actor_w,
    const float* __restrict__ actor_b, const float* __restrict__ critic_w,
    const float* __restrict__ critic_b, float* __restrict__ out, int bofs)
{
    __shared__ float sred[4][4];
    __shared__ float sg;
    __shared__ int sestar;
    int bl = blockIdx.x, tid = threadIdx.x;
    int b = bofs + bl;                     // absolute batch index
    size_t base = (size_t)bl * LL * HD;
    float r0 = 0.f, r1 = 0.f;
    for (int l = 0; l < LL; ++l) {
        size_t o = base + l*HD + tid;
        r0 += bf2f(hhi[o])       + bf2f(hlo[o]);
        r1 += bf2f(hhi[o + 256]) + bf2f(hlo[o + 256]);
    }
    r0 *= (1.0f/LL); r1 *= (1.0f/LL);
    size_t od = base + (LL-1)*HD + tid;
    float dec0 = bf2f(hhi[od])       + bf2f(hlo[od]);
    float dec1 = bf2f(hhi[od + 256]) + bf2f(hlo[od + 256]);

    float p[4];
    #pragma unroll
    for (int e = 0; e < 4; ++e)
        p[e] = r0 * gate_w[tid*4 + e] + r1 * gate_w[(tid+256)*4 + e];
    #pragma unroll
    for (int e = 0; e < 4; ++e) {
        float v = p[e];
        for (int off = 32; off; off >>= 1) v += __shfl_down(v, off);
        p[e] = v;
    }
    int lane = tid & 63, wid = tid >> 6;
    if (!lane) { for (int e = 0; e < 4; ++e) sred[wid][e] = p[e]; }
    __syncthreads();
    if (!tid) {
        float ge[4]; float mx = -1e30f;
        for (int e = 0; e < 4; ++e) {
            ge[e] = sred[0][e]+sred[1][e]+sred[2][e]+sred[3][e] + gate_b[e] + gumbel[b*4 + e];
            if (ge[e] > mx) mx = ge[e];
        }
        float ys[4], den = 0.f;
        for (int e = 0; e < 4; ++e) { ys[e] = expf(ge[e] - mx); den += ys[e]; }
        int estar = 0; float best = ge[0];
        for (int e = 1; e < 4; ++e) if (ge[e] > best) { best = ge[e]; estar = e; }
        float ye = ys[estar] / den;
        float gv = (1.0f + ye) - ye;          // exactly as reference: (hard + y) - y
        for (int e = 0; e < 4; ++e) out[2048 + b*4 + e] = (e == estar) ? gv : 0.0f;
        sg = gv; sestar = estar;
    }
    __syncthreads();
    float gv = sg; int estar = sestar;
    const float* aw  = actor_w  + (size_t)estar * HD * 3;
    const float* cwp = critic_w + (size_t)estar * HD;
    float q[4];
    #pragma unroll
    for (int a = 0; a < 3; ++a)
        q[a] = dec0 * aw[tid*3 + a] + dec1 * aw[(tid+256)*3 + a];
    q[3] = dec0 * cwp[tid] + dec1 * cwp[tid + 256];
    #pragma unroll
    for (int e = 0; e < 4; ++e) {
        float v = q[e];
        for (int off = 32; off; off >>= 1) v += __shfl_down(v, off);
        q[e] = v;
    }
    __syncthreads();
    if (!lane) { for (int e = 0; e < 4; ++e) sred[wid][e] = q[e]; }
    __syncthreads();
    if (!tid) {
        for (int a = 0; a < 3; ++a) {
            float v = sred[0][a]+sred[1][a]+sred[2][a]+sred[3][a];
            out[b*3 + a] = gv * (v + actor_b[estar*3 + a]);
        }
        float v = sred[0][3]+sred[1][3]+sred[2][3]+sred[3][3];
        out[1536 + b] = gv * (v + critic_b[estar]);
    }
}

extern "C" void kernel_launch(void* const* d_in, const int* in_sizes, int n_in,
                              void* d_out, int out_size, void* d_ws, size_t ws_size,
                              hipStream_t stream)
{
    const float* x        = (const float*)d_in[0];
    const float* gumbel   = (const float*)d_in[1];
    const float* w0       = (const float*)d_in[2];
    const float* b0       = (const float*)d_in[3];
    const float* ln_g     = (const float*)d_in[4];
    const float* ln_b     = (const float*)d_in[5];
    const float* gate_w   = (const float*)d_in[6];
    const float* gate_b   = (const float*)d_in[7];
    const float* actor_w  = (const float*)d_in[8];
    const float* actor_b  = (const float*)d_in[9];
    const float* critic_w = (const float*)d_in[10];
    const float* critic_b = (const float*)d_in[11];
    const float* in_w[2]   = {(const float*)d_in[12], (const float*)d_in[22]};
    const float* in_b[2]   = {(const float*)d_in[13], (const float*)d_in[23]};
    const float* conv_w[2] = {(const float*)d_in[14], (const float*)d_in[24]};
    const float* conv_b[2] = {(const float*)d_in[15], (const float*)d_in[25]};
    const float* xp_w[2]   = {(const float*)d_in[16], (const float*)d_in[26]};
    const float* xp_b[2]   = {(const float*)d_in[17], (const float*)d_in[27]};
    const float* dt_w[2]   = {(const float*)d_in[18], (const float*)d_in[28]};
    const float* dt_b[2]   = {(const float*)d_in[19], (const float*)d_in[29]};
    const float* out_w[2]  = {(const float*)d_in[20], (const float*)d_in[30]};
    const float* out_b[2]  = {(const float*)d_in[21], (const float*)d_in[31]};

    // Per-row scratch: xb(2048) + hhi(1024)+hlo(1024) + Abig_hi(2048)+Abig_lo(2048) = 8192 B
    int CB = 512;
    while (CB > 1 && (size_t)CB * LL * 8192 + (16u << 20) > ws_size) CB >>= 1;
    const int rows = CB * LL;
    const size_t CSZ = (size_t)rows * HD;        // elements per 512-wide buffer

    char* p = (char*)d_ws;
    float* xb = (float*)p;  p += CSZ * 4;
    unsigned short* hhi = (unsigned short*)p; p += CSZ * 2;
    unsigned short* hlo = (unsigned short*)p; p += CSZ * 2;
    unsigned short* Abig_hi = (unsigned short*)p; p += CSZ * 2 * 2;  // rows x 1024 bf16
    unsigned short* Abig_lo = (unsigned short*)p; p += CSZ * 2 * 2;
    unsigned short* wtb = (unsigned short*)p;  p += (size_t)8 * 524288 * 2;
    unsigned short* iwh[2] = {wtb,            wtb + 4*524288};
    unsigned short* iwl[2] = {wtb +   524288, wtb + 5*524288};
    unsigned short* owh[2] = {wtb + 2*524288, wtb + 6*524288};
    unsigned short* owl[2] = {wtb + 3*524288, wtb + 7*524288};
    float* xpwT[2] = {(float*)p, (float*)p + 8192};

    // weight transforms (cheap, every call)
    for (int m = 0; m < 2; ++m) {
        k_cvt_wt<<<2048, 256, 0, stream>>>(in_w[m],  iwh[m], iwl[m], 1024,  9); // K=512,N=1024
        k_cvt_wt<<<2048, 256, 0, stream>>>(out_w[m], owh[m], owl[m],  512, 10); // K=1024,N=512
        k_tr16<<<32, 256, 0, stream>>>(xp_w[m], xpwT[m]);
    }

    const int nchunk = BB / CB;
    for (int c = 0; c < nchunk; ++c) {
        const float* xin = x + (size_t)c * CB * LL * FD;
        k_embed<<<rows*HD/256, 256, 0, stream>>>(xin, w0, b0, hhi, hlo);
        for (int m = 0; m < 2; ++m) {
            // in_proj: zi = h @ in_w + in_b ; z->silu->Abig[:,512:], xi->xb
            k_mgemm<512, 0><<<dim3(8, rows/128), 256, 0, stream>>>(
                hhi, hlo, iwh[m], iwl[m], in_b[m], nullptr, nullptr, xb, Abig_hi, Abig_lo);
            // fused conv+silu+dt: xb -> Abig[:,0:512] (bf16 hi/lo)
            k_cdt<<<rows/16, 256, 0, stream>>>(xb, conv_w[m], conv_b[m],
                xpwT[m], xp_b[m], dt_w[m], dt_b[m], Abig_hi, Abig_lo);
            // out_proj: Abig @ out_w + out_b + (hhi+hlo) -> xb (pre-LN fp32)
            k_mgemm<1024, 1><<<dim3(4, rows/128), 256, 0, stream>>>(
                Abig_hi, Abig_lo, owh[m], owl[m], out_b[m], hhi, hlo, xb, nullptr, nullptr);
            // LN -> hhi/hlo bf16 (h for residual/head reconstructed as hi+lo)
            k_ln<<<rows, 256, 0, stream>>>(xb, ln_g, ln_b, hhi, hlo);
        }
        k_head<<<CB, 256, 0, stream>>>(hhi, hlo, gumbel, gate_w, gate_b, actor_w, actor_b,
                                       critic_w, critic_b, (float*)d_out, c*CB);
    }
}

// Round 5
// 2198.630 us; speedup vs baseline: 1.2058x; 1.2058x over previous
//
#include <hip/hip_runtime.h>
#include <math.h>

#define BB 512
#define LL 128
#define FD 8
#define HD 512
#define EPSV 1e-5f

typedef __attribute__((ext_vector_type(8))) __bf16 bf16x8;
typedef __attribute__((ext_vector_type(4))) float floatx4;
typedef __attribute__((ext_vector_type(4))) unsigned short us4;
typedef __attribute__((ext_vector_type(8))) unsigned short us8;

__device__ __forceinline__ float silu_f(float x){ return x / (1.0f + expf(-x)); }
__device__ __forceinline__ float softplus_f(float x){ return (x > 20.0f) ? x : log1pf(expf(x)); }

__device__ __forceinline__ unsigned short f2bf(float x){
    union { float f; unsigned u; } v; v.f = x;
    unsigned r = v.u + 0x7fffu + ((v.u >> 16) & 1u);   // RNE
    return (unsigned short)(r >> 16);
}
__device__ __forceinline__ float bf2f(unsigned short h){
    union { unsigned u; float f; } v; v.u = ((unsigned)h) << 16; return v.f;
}
__device__ __forceinline__ void split_bf(float x, unsigned short* hi, unsigned short* lo){
    unsigned short h = f2bf(x);
    *hi = h;
    *lo = f2bf(x - bf2f(h));
}

// ---------------- embed: h = x @ w0 + b0 -> hi/lo bf16 only ----------------
__global__ __launch_bounds__(256) void k_embed(const float* __restrict__ x,
    const float* __restrict__ w0, const float* __restrict__ b0,
    unsigned short* __restrict__ hhi, unsigned short* __restrict__ hlo)
{
    int idx = blockIdx.x*256 + threadIdx.x;      // over rows*HD
    int c = idx & (HD-1);
    int row = idx >> 9;
    const float* xr = x + (size_t)row*FD;
    float acc = b0[c];
    #pragma unroll
    for (int f=0; f<FD; ++f) acc = fmaf(xr[f], w0[f*HD + c], acc);
    unsigned short hi, lo; split_bf(acc, &hi, &lo);
    hhi[idx] = hi; hlo[idx] = lo;
}

// ---------------- weight transpose + hi/lo split: W[K][N] fp32 -> Wt[N][K] bf16 ----------------
__global__ __launch_bounds__(256) void k_cvt_wt(const float* __restrict__ W,
    unsigned short* __restrict__ Thi, unsigned short* __restrict__ Tlo, int N, int kbits)
{
    int idx = blockIdx.x*256 + threadIdx.x;      // over N*K, k fastest
    int K = 1 << kbits;
    int n = idx >> kbits, k = idx & (K-1);
    float v = W[(size_t)k*N + n];
    unsigned short hi, lo; split_bf(v, &hi, &lo);
    Thi[idx] = hi; Tlo[idx] = lo;
}

// ---------------- U = xp_w(512x16) @ dt_w(16x512) -> [n][c] bf16 hi/lo (B-layout) ----------------
__global__ __launch_bounds__(256) void k_mkU(const float* __restrict__ xp_w,
    const float* __restrict__ dt_w,
    unsigned short* __restrict__ Uhi, unsigned short* __restrict__ Ulo)
{
    int idx = blockIdx.x*256 + threadIdx.x;      // over 512*512, c fastest
    int n = idx >> 9, c = idx & 511;
    float acc = 0.0f;
    #pragma unroll
    for (int j = 0; j < 16; ++j) acc = fmaf(xp_w[c*16 + j], dt_w[j*512 + n], acc);
    unsigned short hi, lo; split_bf(acc, &hi, &lo);
    Uhi[idx] = hi; Ulo[idx] = lo;
}

// ---------------- biasU[n] = xp_b @ dt_w[:,n] + dt_b[n] ----------------
__global__ __launch_bounds__(256) void k_dtbias(const float* __restrict__ xp_b,
    const float* __restrict__ dt_w, const float* __restrict__ dt_b,
    float* __restrict__ biasU)
{
    int n = blockIdx.x*256 + threadIdx.x;        // 512
    float acc = dt_b[n];
    #pragma unroll
    for (int j = 0; j < 16; ++j) acc = fmaf(xp_b[j], dt_w[j*512 + n], acc);
    biasU[n] = acc;
}

// ---------------- split-bf16 MFMA GEMM, 128x128 tile, 4 waves, 16x16x32 ----------------
// C = A(MxK) @ Wt(NxK)^T, acc fp32 via hi*hi + hi*lo + lo*hi.
// MODE 0 (in_proj, K=512, N=1024): col<512 -> silu -> oA[row][512+col] bf16 hi/lo
//                                  col>=512 -> outF[row][col-512] fp32 (xi)
// MODE 1 (out_proj, K=1024, N=512): outF = v + bias + (rhi+rlo) fp32 (pre-LN)
// MODE 2 (dt, K=512, N=512): A=xc; out = xc[row][col] * softplus(v+biasU) -> oA[row][col] hi/lo
template<int KDIM, int MODE>
__global__ __launch_bounds__(256) void k_mgemm(
    const unsigned short* __restrict__ Ahi, const unsigned short* __restrict__ Alo,
    const unsigned short* __restrict__ Bhi, const unsigned short* __restrict__ Blo,
    const float* __restrict__ bias,
    const unsigned short* __restrict__ rhi, const unsigned short* __restrict__ rlo,
    float* __restrict__ outF,
    unsigned short* __restrict__ oAhi, unsigned short* __restrict__ oAlo)
{
    __shared__ unsigned short lds[4 * 4096];     // 4 tiles of 128x32 bf16 (8 KB each)
    const int tid  = threadIdx.x;
    const int wv   = tid >> 6, lane = tid & 63;
    const int quad = lane >> 4, l16 = lane & 15;
    const size_t mBase = (size_t)blockIdx.y * 128;
    const int nBase = blockIdx.x * 128;
    const int wm = (wv & 1) * 64, wn = (wv >> 1) * 64;

    floatx4 acc[4][4] = {};

    const int rowIn = lane >> 2;                 // 0..15
    const int kofs  = (lane & 3) * 8;            // bf16 units within 32-wide k tile
    const unsigned short* gsrc[4];
    gsrc[0] = Ahi + mBase * KDIM;
    gsrc[1] = Alo + mBase * KDIM;
    gsrc[2] = Bhi + (size_t)nBase * KDIM;
    gsrc[3] = Blo + (size_t)nBase * KDIM;

    for (int k0 = 0; k0 < KDIM; k0 += 32) {
        #pragma unroll
        for (int b = 0; b < 4; ++b) {
            #pragma unroll
            for (int r = 0; r < 2; ++r) {
                int row = r * 64 + wv * 16 + rowIn;
                const unsigned short* g = gsrc[b] + (size_t)row * KDIM + k0 + kofs;
                unsigned short* l = &lds[b * 4096 + r * 2048 + wv * 512]; // +lane*16B implicit
                __builtin_amdgcn_global_load_lds(
                    (const __attribute__((address_space(1))) void*)g,
                    (__attribute__((address_space(3))) void*)l, 16, 0, 0);
            }
        }
        __syncthreads();
        bf16x8 ah[4], al[4], bh[4], bl[4];
        #pragma unroll
        for (int i = 0; i < 4; ++i) {
            int am = wm + 16*i + l16;
            ah[i] = *(const bf16x8*)&lds[0*4096 + am*32 + quad*8];
            al[i] = *(const bf16x8*)&lds[1*4096 + am*32 + quad*8];
            int bn = wn + 16*i + l16;
            bh[i] = *(const bf16x8*)&lds[2*4096 + bn*32 + quad*8];
            bl[i] = *(const bf16x8*)&lds[3*4096 + bn*32 + quad*8];
        }
        #pragma unroll
        for (int i = 0; i < 4; ++i)
            #pragma unroll
            for (int j = 0; j < 4; ++j) {
                acc[i][j] = __builtin_amdgcn_mfma_f32_16x16x32_bf16(ah[i], bh[j], acc[i][j], 0, 0, 0);
                acc[i][j] = __builtin_amdgcn_mfma_f32_16x16x32_bf16(ah[i], bl[j], acc[i][j], 0, 0, 0);
                acc[i][j] = __builtin_amdgcn_mfma_f32_16x16x32_bf16(al[i], bh[j], acc[i][j], 0, 0, 0);
            }
        __syncthreads();
    }

    // epilogue: D[row=(quad*4+r) within 16, col=l16 within 16]
    #pragma unroll
    for (int i = 0; i < 4; ++i) {
        #pragma unroll
        for (int r = 0; r < 4; ++r) {
            size_t row = mBase + wm + 16*i + quad*4 + r;
            #pragma unroll
            for (int j = 0; j < 4; ++j) {
                int col = nBase + wn + 16*j + l16;
                float v = acc[i][j][r] + bias[col];
                if (MODE == 0) {
                    if (col < 512) {
                        float s = silu_f(v);
                        unsigned short hi, lo; split_bf(s, &hi, &lo);
                        oAhi[row*1024 + 512 + col] = hi;
                        oAlo[row*1024 + 512 + col] = lo;
                    } else {
                        outF[row*512 + (col - 512)] = v;
                    }
                } else if (MODE == 1) {
                    size_t idx = row*512 + col;
                    v += bf2f(rhi[idx]) + bf2f(rlo[idx]);
                    outF[idx] = v;
                } else {
                    size_t aidx = row*512 + col;
                    float xcv = bf2f(Ahi[aidx]) + bf2f(Alo[aidx]);
                    float o = xcv * softplus_f(v);
                    unsigned short hi, lo; split_bf(o, &hi, &lo);
                    oAhi[row*1024 + col] = hi;
                    oAlo[row*1024 + col] = lo;
                }
            }
        }
    }
}

// ---------------- depthwise conv3 (pad 1) + bias + silu -> xc bf16 hi/lo ----------------
__global__ __launch_bounds__(256) void k_conv(const float* __restrict__ xb,
    const float* __restrict__ cw, const float* __restrict__ cb,
    unsigned short* __restrict__ xchi, unsigned short* __restrict__ xclo)
{
    int t = blockIdx.x*256 + threadIdx.x;        // over rows*128 (4 channels each)
    int c4 = (t & 127) << 2;
    size_t row = (size_t)(t >> 7);
    int l = (int)(row & (LL-1));
    const float* base = xb + row*512 + c4;
    float4 xm = make_float4(0.f,0.f,0.f,0.f), xp = make_float4(0.f,0.f,0.f,0.f);
    if (l > 0)      xm = *(const float4*)(base - 512);
    float4 x0 = *(const float4*)base;
    if (l < LL-1)   xp = *(const float4*)(base + 512);
    us4 h4, l4;
    const float* pm = &xm.x; const float* p0 = &x0.x; const float* pp = &xp.x;
    #pragma unroll
    for (int k = 0; k < 4; ++k) {
        int c = c4 + k;
        float v = cb[c];
        v = fmaf(pm[k], cw[c*3+0], v);
        v = fmaf(p0[k], cw[c*3+1], v);
        v = fmaf(pp[k], cw[c*3+2], v);
        v = silu_f(v);
        unsigned short hi, lo; split_bf(v, &hi, &lo);
        h4[k] = hi; l4[k] = lo;
    }
    *(us4*)(xchi + row*512 + c4) = h4;
    *(us4*)(xclo + row*512 + c4) = l4;
}

// ---------------- layernorm, one wave per row, shuffle-only ----------------
__global__ __launch_bounds__(256) void k_ln(const float* __restrict__ in,
    const float* __restrict__ g, const float* __restrict__ b,
    unsigned short* __restrict__ ohi, unsigned short* __restrict__ olo)
{
    int wv = threadIdx.x >> 6, lane = threadIdx.x & 63;
    size_t row = (size_t)blockIdx.x * 4 + wv;
    const float* r = in + row*512 + lane*8;
    float4 v0 = *(const float4*)r;
    float4 v1 = *(const float4*)(r + 4);
    float s = (v0.x+v0.y)+(v0.z+v0.w) + (v1.x+v1.y)+(v1.z+v1.w);
    float q = (v0.x*v0.x+v0.y*v0.y)+(v0.z*v0.z+v0.w*v0.w)
            + (v1.x*v1.x+v1.y*v1.y)+(v1.z*v1.z+v1.w*v1.w);
    #pragma unroll
    for (int off = 32; off; off >>= 1) { s += __shfl_xor(s, off); q += __shfl_xor(q, off); }
    float mu = s * (1.0f/512.0f);
    float rs = rsqrtf(q*(1.0f/512.0f) - mu*mu + EPSV);
    const float* gp = g + lane*8;
    const float* bp = b + lane*8;
    float4 g0 = *(const float4*)gp, g1 = *(const float4*)(gp+4);
    float4 b0 = *(const float4*)bp, b1 = *(const float4*)(bp+4);
    float vals[8] = {v0.x,v0.y,v0.z,v0.w,v1.x,v1.y,v1.z,v1.w};
    float gs[8] = {g0.x,g0.y,g0.z,g0.w,g1.x,g1.y,g1.z,g1.w};
    float bs[8] = {b0.x,b0.y,b0.z,b0.w,b1.x,b1.y,b1.z,b1.w};
    us8 hh, ll;
    #pragma unroll
    for (int k = 0; k < 8; ++k) {
        float o = (vals[k] - mu) * rs * gs[k] + bs[k];
        unsigned short hi, lo; split_bf(o, &hi, &lo);
        hh[k] = hi; ll[k] = lo;
    }
    *(us8*)(ohi + row*512 + lane*8) = hh;
    *(us8*)(olo + row*512 + lane*8) = ll;
}

// ---------------- head: reg/dec, gate softmax+argmax, expert select ----------------
__global__ __launch_bounds__(256) void k_head(
    const unsigned short* __restrict__ hhi, const unsigned short* __restrict__ hlo,
    const float* __restrict__ gumbel, const float* __restrict__ gate_w,
    const float* __restrict__ gate_b, const float* __restrict__ actor_w,
    const float* __restrict__ actor_b, const float* __restrict__ critic_w,
    const float* __restrict__ critic_b, float* __restrict__ out, int bofs)
{
    __shared__ float sred[4][4];
    __shared__ float sg;
    __shared__ int sestar;
    int bl = blockIdx.x, tid = threadIdx.x;
    int b = bofs + bl;                     // absolute batch index
    size_t base = (size_t)bl * LL * HD;
    float r0 = 0.f, r1 = 0.f;
    for (int l = 0; l < LL; ++l) {
        size_t o = base + l*HD + tid;
        r0 += bf2f(hhi[o])       + bf2f(hlo[o]);
        r1 += bf2f(hhi[o + 256]) + bf2f(hlo[o + 256]);
    }
    r0 *= (1.0f/LL); r1 *= (1.0f/LL);
    size_t od = base + (LL-1)*HD + tid;
    float dec0 = bf2f(hhi[od])       + bf2f(hlo[od]);
    float dec1 = bf2f(hhi[od + 256]) + bf2f(hlo[od + 256]);

    float p[4];
    #pragma unroll
    for (int e = 0; e < 4; ++e)
        p[e] = r0 * gate_w[tid*4 + e] + r1 * gate_w[(tid+256)*4 + e];
    #pragma unroll
    for (int e = 0; e < 4; ++e) {
        float v = p[e];
        for (int off = 32; off; off >>= 1) v += __shfl_down(v, off);
        p[e] = v;
    }
    int lane = tid & 63, wid = tid >> 6;
    if (!lane) { for (int e = 0; e < 4; ++e) sred[wid][e] = p[e]; }
    __syncthreads();
    if (!tid) {
        float ge[4]; float mx = -1e30f;
        for (int e = 0; e < 4; ++e) {
            ge[e] = sred[0][e]+sred[1][e]+sred[2][e]+sred[3][e] + gate_b[e] + gumbel[b*4 + e];
            if (ge[e] > mx) mx = ge[e];
        }
        float ys[4], den = 0.f;
        for (int e = 0; e < 4; ++e) { ys[e] = expf(ge[e] - mx); den += ys[e]; }
        int estar = 0; float best = ge[0];
        for (int e = 1; e < 4; ++e) if (ge[e] > best) { best = ge[e]; estar = e; }
        float ye = ys[estar] / den;
        float gv = (1.0f + ye) - ye;          // exactly as reference: (hard + y) - y
        for (int e = 0; e < 4; ++e) out[2048 + b*4 + e] = (e == estar) ? gv : 0.0f;
        sg = gv; sestar = estar;
    }
    __syncthreads();
    float gv = sg; int estar = sestar;
    const float* aw  = actor_w  + (size_t)estar * HD * 3;
    const float* cwp = critic_w + (size_t)estar * HD;
    float q[4];
    #pragma unroll
    for (int a = 0; a < 3; ++a)
        q[a] = dec0 * aw[tid*3 + a] + dec1 * aw[(tid+256)*3 + a];
    q[3] = dec0 * cwp[tid] + dec1 * cwp[tid + 256];
    #pragma unroll
    for (int e = 0; e < 4; ++e) {
        float v = q[e];
        for (int off = 32; off; off >>= 1) v += __shfl_down(v, off);
        q[e] = v;
    }
    __syncthreads();
    if (!lane) { for (int e = 0; e < 4; ++e) sred[wid][e] = q[e]; }
    __syncthreads();
    if (!tid) {
        for (int a = 0; a < 3; ++a) {
            float v = sred[0][a]+sred[1][a]+sred[2][a]+sred[3][a];
            out[b*3 + a] = gv * (v + actor_b[estar*3 + a]);
        }
        float v = sred[0][3]+sred[1][3]+sred[2][3]+sred[3][3];
        out[1536 + b] = gv * (v + critic_b[estar]);
    }
}

extern "C" void kernel_launch(void* const* d_in, const int* in_sizes, int n_in,
                              void* d_out, int out_size, void* d_ws, size_t ws_size,
                              hipStream_t stream)
{
    const float* x        = (const float*)d_in[0];
    const float* gumbel   = (const float*)d_in[1];
    const float* w0       = (const float*)d_in[2];
    const float* b0       = (const float*)d_in[3];
    const float* ln_g     = (const float*)d_in[4];
    const float* ln_b     = (const float*)d_in[5];
    const float* gate_w   = (const float*)d_in[6];
    const float* gate_b   = (const float*)d_in[7];
    const float* actor_w  = (const float*)d_in[8];
    const float* actor_b  = (const float*)d_in[9];
    const float* critic_w = (const float*)d_in[10];
    const float* critic_b = (const float*)d_in[11];
    const float* in_w[2]   = {(const float*)d_in[12], (const float*)d_in[22]};
    const float* in_b[2]   = {(const float*)d_in[13], (const float*)d_in[23]};
    const float* conv_w[2] = {(const float*)d_in[14], (const float*)d_in[24]};
    const float* conv_b[2] = {(const float*)d_in[15], (const float*)d_in[25]};
    const float* xp_w[2]   = {(const float*)d_in[16], (const float*)d_in[26]};
    const float* xp_b[2]   = {(const float*)d_in[17], (const float*)d_in[27]};
    const float* dt_w[2]   = {(const float*)d_in[18], (const float*)d_in[28]};
    const float* dt_b[2]   = {(const float*)d_in[19], (const float*)d_in[29]};
    const float* out_w[2]  = {(const float*)d_in[20], (const float*)d_in[30]};
    const float* out_b[2]  = {(const float*)d_in[21], (const float*)d_in[31]};

    // Per-row scratch: xb(2048) + hhi/hlo(2048) + xchi/xclo(2048) + Abig hi/lo(4096) = 10240 B
    int CB = 512;
    while (CB > 1 && (size_t)CB * LL * 10240 + (16u << 20) > ws_size) CB >>= 1;
    const int rows = CB * LL;
    const size_t CSZ = (size_t)rows * HD;        // elements per 512-wide buffer

    char* p = (char*)d_ws;
    float* xb = (float*)p;  p += CSZ * 4;
    unsigned short* hhi = (unsigned short*)p; p += CSZ * 2;
    unsigned short* hlo = (unsigned short*)p; p += CSZ * 2;
    unsigned short* xchi = (unsigned short*)p; p += CSZ * 2;
    unsigned short* xclo = (unsigned short*)p; p += CSZ * 2;
    unsigned short* Abig_hi = (unsigned short*)p; p += CSZ * 2 * 2;  // rows x 1024 bf16
    unsigned short* Abig_lo = (unsigned short*)p; p += CSZ * 2 * 2;
    unsigned short* wtb = (unsigned short*)p;  p += (size_t)8 * 524288 * 2;
    unsigned short* iwh[2] = {wtb,            wtb + 4*524288};
    unsigned short* iwl[2] = {wtb +   524288, wtb + 5*524288};
    unsigned short* owh[2] = {wtb + 2*524288, wtb + 6*524288};
    unsigned short* owl[2] = {wtb + 3*524288, wtb + 7*524288};
    unsigned short* Uhi[2] = {(unsigned short*)p, (unsigned short*)p + 262144}; p += 262144u * 2 * 2;
    unsigned short* Ulo[2] = {(unsigned short*)p, (unsigned short*)p + 262144}; p += 262144u * 2 * 2;
    float* biasU[2] = {(float*)p, (float*)p + 512};

    // weight transforms (cheap, every call)
    for (int m = 0; m < 2; ++m) {
        k_cvt_wt<<<2048, 256, 0, stream>>>(in_w[m],  iwh[m], iwl[m], 1024,  9); // K=512,N=1024
        k_cvt_wt<<<2048, 256, 0, stream>>>(out_w[m], owh[m], owl[m],  512, 10); // K=1024,N=512
        k_mkU<<<1024, 256, 0, stream>>>(xp_w[m], dt_w[m], Uhi[m], Ulo[m]);
        k_dtbias<<<2, 256, 0, stream>>>(xp_b[m], dt_w[m], dt_b[m], biasU[m]);
    }

    const int nchunk = BB / CB;
    for (int c = 0; c < nchunk; ++c) {
        const float* xin = x + (size_t)c * CB * LL * FD;
        k_embed<<<rows*HD/256, 256, 0, stream>>>(xin, w0, b0, hhi, hlo);
        for (int m = 0; m < 2; ++m) {
            // in_proj: zi = h @ in_w + in_b ; z->silu->Abig[:,512:], xi->xb
            k_mgemm<512, 0><<<dim3(8, rows/128), 256, 0, stream>>>(
                hhi, hlo, iwh[m], iwl[m], in_b[m], nullptr, nullptr, xb, Abig_hi, Abig_lo);
            // conv+silu -> xc bf16 hi/lo
            k_conv<<<rows*128/256, 256, 0, stream>>>(xb, conv_w[m], conv_b[m], xchi, xclo);
            // dt GEMM: dt_pre = xc @ U + biasU; out = xc*softplus -> Abig[:,0:512]
            k_mgemm<512, 2><<<dim3(4, rows/128), 256, 0, stream>>>(
                xchi, xclo, Uhi[m], Ulo[m], biasU[m], nullptr, nullptr, nullptr, Abig_hi, Abig_lo);
            // out_proj: Abig @ out_w + out_b + (hhi+hlo) -> xb (pre-LN fp32)
            k_mgemm<1024, 1><<<dim3(4, rows/128), 256, 0, stream>>>(
                Abig_hi, Abig_lo, owh[m], owl[m], out_b[m], hhi, hlo, xb, nullptr, nullptr);
            // LN -> hhi/hlo bf16
            k_ln<<<rows/4, 256, 0, stream>>>(xb, ln_g, ln_b, hhi, hlo);
        }
        k_head<<<CB, 256, 0, stream>>>(hhi, hlo, gumbel, gate_w, gate_b, actor_w, actor_b,
                                       critic_w, critic_b, (float*)d_out, c*CB);
    }
}

// Round 6
// 2031.887 us; speedup vs baseline: 1.3048x; 1.0821x over previous
//
#include <hip/hip_runtime.h>
#include <math.h>

#define BB 512
#define LL 128
#define FD 8
#define HD 512
#define EPSV 1e-5f

typedef __attribute__((ext_vector_type(8))) __bf16 bf16x8;
typedef __attribute__((ext_vector_type(4))) float floatx4;
typedef __attribute__((ext_vector_type(8))) unsigned short us8;

__device__ __forceinline__ float silu_f(float x){ return x / (1.0f + expf(-x)); }
__device__ __forceinline__ float softplus_f(float x){ return (x > 20.0f) ? x : log1pf(expf(x)); }

__device__ __forceinline__ unsigned short f2bf(float x){
    union { float f; unsigned u; } v; v.f = x;
    unsigned r = v.u + 0x7fffu + ((v.u >> 16) & 1u);   // RNE
    return (unsigned short)(r >> 16);
}
__device__ __forceinline__ float bf2f(unsigned short h){
    union { unsigned u; float f; } v; v.u = ((unsigned)h) << 16; return v.f;
}
__device__ __forceinline__ void split_bf(float x, unsigned short* hi, unsigned short* lo){
    unsigned short h = f2bf(x);
    *hi = h;
    *lo = f2bf(x - bf2f(h));
}

// ---------------- embed: h = x @ w0 + b0 -> hi/lo bf16 ----------------
__global__ __launch_bounds__(256) void k_embed(const float* __restrict__ x,
    const float* __restrict__ w0, const float* __restrict__ b0,
    unsigned short* __restrict__ hhi, unsigned short* __restrict__ hlo)
{
    int idx = blockIdx.x*256 + threadIdx.x;      // over rows*HD
    int c = idx & (HD-1);
    int row = idx >> 9;
    const float* xr = x + (size_t)row*FD;
    float acc = b0[c];
    #pragma unroll
    for (int f=0; f<FD; ++f) acc = fmaf(xr[f], w0[f*HD + c], acc);
    unsigned short hi, lo; split_bf(acc, &hi, &lo);
    hhi[idx] = hi; hlo[idx] = lo;
}

// ---------------- weight transpose+split for BOTH layers: W[K][N] -> Wt[N][K] bf16 hi/lo ----------------
__global__ __launch_bounds__(256) void k_cvt2(const float* __restrict__ W0,
    const float* __restrict__ W1,
    unsigned short* __restrict__ Th0, unsigned short* __restrict__ Tl0,
    unsigned short* __restrict__ Th1, unsigned short* __restrict__ Tl1,
    int N, int kbits)
{
    int total = N << kbits;
    int idx = blockIdx.x*256 + threadIdx.x;
    const float* W = W0; unsigned short* Th = Th0; unsigned short* Tl = Tl0;
    if (idx >= total) { idx -= total; W = W1; Th = Th1; Tl = Tl1; }
    int K = 1 << kbits;
    int n = idx >> kbits, k = idx & (K-1);
    float v = W[(size_t)k*N + n];
    unsigned short hi, lo; split_bf(v, &hi, &lo);
    Th[idx] = hi; Tl[idx] = lo;
}

// ---------------- U = xp_w @ dt_w (512x512, B-layout [n][c]) + biasU, both layers ----------------
__global__ __launch_bounds__(256) void k_mkU2(
    const float* __restrict__ xw0, const float* __restrict__ dw0,
    const float* __restrict__ xpb0, const float* __restrict__ dtb0,
    const float* __restrict__ xw1, const float* __restrict__ dw1,
    const float* __restrict__ xpb1, const float* __restrict__ dtb1,
    unsigned short* __restrict__ Uhi0, unsigned short* __restrict__ Ulo0,
    unsigned short* __restrict__ Uhi1, unsigned short* __restrict__ Ulo1,
    float* __restrict__ bU0, float* __restrict__ bU1)
{
    int blk = blockIdx.x, tid = threadIdx.x;
    if (blk < 2048) {
        int layer = blk >> 10;
        const float* xw = layer ? xw1 : xw0;
        const float* dw = layer ? dw1 : dw0;
        unsigned short* Uh = layer ? Uhi1 : Uhi0;
        unsigned short* Ul = layer ? Ulo1 : Ulo0;
        int idx = (blk & 1023)*256 + tid;        // n*512 + c, c fastest
        int n = idx >> 9, c = idx & 511;
        float acc = 0.0f;
        #pragma unroll
        for (int j = 0; j < 16; ++j) acc = fmaf(xw[c*16 + j], dw[j*512 + n], acc);
        unsigned short hi, lo; split_bf(acc, &hi, &lo);
        Uh[idx] = hi; Ul[idx] = lo;
    } else {
        int q = blk - 2048;                      // 0..3
        int layer = q >> 1;
        const float* xpb = layer ? xpb1 : xpb0;
        const float* dw  = layer ? dw1  : dw0;
        const float* dtb = layer ? dtb1 : dtb0;
        float* bU = layer ? bU1 : bU0;
        int n = (q & 1)*256 + tid;
        float acc = dtb[n];
        #pragma unroll
        for (int j = 0; j < 16; ++j) acc = fmaf(xpb[j], dw[j*512 + n], acc);
        bU[n] = acc;
    }
}

// ---------------- split-bf16 MFMA GEMM, 128x128 tile, 4 waves, 16x16x32 ----------------
// MODE 0 (in_proj, K=512, N=1024):
//    nBase<512  (z):  silu -> Abig[row][512+col] bf16 hi/lo
//    nBase>=512 (xi): fused depthwise conv3+silu along rows (M-tile = one full batch
//                     sequence), output -> xc[row][col-512] bf16 hi/lo
// MODE 1 (out_proj, K=1024, N=512): outF = v + bias (fp32, pre-LN; residual added in k_ln)
// MODE 2 (dt, K=512, N=512): A=xc; out = xc * softplus(v+biasU) -> Abig[row][col] hi/lo
template<int KDIM, int MODE>
__global__ __launch_bounds__(256) void k_mgemm(
    const unsigned short* __restrict__ Ahi, const unsigned short* __restrict__ Alo,
    const unsigned short* __restrict__ Bhi, const unsigned short* __restrict__ Blo,
    const float* __restrict__ bias,
    const float* __restrict__ cw, const float* __restrict__ cb,
    float* __restrict__ outF,
    unsigned short* __restrict__ oAhi, unsigned short* __restrict__ oAlo,
    unsigned short* __restrict__ xchi, unsigned short* __restrict__ xclo)
{
    __shared__ __align__(16) char smem[33280];   // staging 32KB; conv scratch 33.28KB
    unsigned short* lds = (unsigned short*)smem;
    const int tid  = threadIdx.x;
    const int wv   = tid >> 6, lane = tid & 63;
    const int quad = lane >> 4, l16 = lane & 15;
    const size_t mBase = (size_t)blockIdx.y * 128;
    const int nBase = blockIdx.x * 128;
    const int wm = (wv & 1) * 64, wn = (wv >> 1) * 64;

    floatx4 acc[4][4] = {};

    const int rowIn = lane >> 2;                 // 0..15
    const int kofs  = (lane & 3) * 8;            // bf16 units within 32-wide k tile
    const unsigned short* gsrc[4];
    gsrc[0] = Ahi + mBase * KDIM;
    gsrc[1] = Alo + mBase * KDIM;
    gsrc[2] = Bhi + (size_t)nBase * KDIM;
    gsrc[3] = Blo + (size_t)nBase * KDIM;

    for (int k0 = 0; k0 < KDIM; k0 += 32) {
        #pragma unroll
        for (int b = 0; b < 4; ++b) {
            #pragma unroll
            for (int r = 0; r < 2; ++r) {
                int row = r * 64 + wv * 16 + rowIn;
                const unsigned short* g = gsrc[b] + (size_t)row * KDIM + k0 + kofs;
                unsigned short* l = &lds[b * 4096 + r * 2048 + wv * 512]; // +lane*16B implicit
                __builtin_amdgcn_global_load_lds(
                    (const __attribute__((address_space(1))) void*)g,
                    (__attribute__((address_space(3))) void*)l, 16, 0, 0);
            }
        }
        __syncthreads();
        bf16x8 ah[4], al[4], bh[4], bl[4];
        #pragma unroll
        for (int i = 0; i < 4; ++i) {
            int am = wm + 16*i + l16;
            ah[i] = *(const bf16x8*)&lds[0*4096 + am*32 + quad*8];
            al[i] = *(const bf16x8*)&lds[1*4096 + am*32 + quad*8];
            int bn = wn + 16*i + l16;
            bh[i] = *(const bf16x8*)&lds[2*4096 + bn*32 + quad*8];
            bl[i] = *(const bf16x8*)&lds[3*4096 + bn*32 + quad*8];
        }
        #pragma unroll
        for (int i = 0; i < 4; ++i)
            #pragma unroll
            for (int j = 0; j < 4; ++j) {
                acc[i][j] = __builtin_amdgcn_mfma_f32_16x16x32_bf16(ah[i], bh[j], acc[i][j], 0, 0, 0);
                acc[i][j] = __builtin_amdgcn_mfma_f32_16x16x32_bf16(ah[i], bl[j], acc[i][j], 0, 0, 0);
                acc[i][j] = __builtin_amdgcn_mfma_f32_16x16x32_bf16(al[i], bh[j], acc[i][j], 0, 0, 0);
            }
        __syncthreads();
    }

    if (MODE == 0 && nBase >= 512) {
        // fused conv3+silu: stage 128x64 fp32 halves of the xi tile in LDS (stride 65)
        float* sc = (float*)smem;
        #pragma unroll
        for (int half = 0; half < 2; ++half) {
            __syncthreads();
            if ((wn >> 6) == half) {
                #pragma unroll
                for (int i = 0; i < 4; ++i)
                    #pragma unroll
                    for (int r = 0; r < 4; ++r) {
                        int rl = wm + 16*i + quad*4 + r;
                        #pragma unroll
                        for (int j = 0; j < 4; ++j) {
                            int cl = 16*j + l16;        // 0..63 within half
                            sc[rl*65 + cl] = acc[i][j][r] + bias[nBase + half*64 + cl];
                        }
                    }
            }
            __syncthreads();
            for (int e = tid; e < 8192; e += 256) {
                int l = e >> 6, cc = e & 63;
                int gcol = (nBase - 512) + half*64 + cc;
                float xm = (l > 0)   ? sc[(l-1)*65 + cc] : 0.0f;
                float x0 = sc[l*65 + cc];
                float xp = (l < 127) ? sc[(l+1)*65 + cc] : 0.0f;
                float v = cb[gcol];
                v = fmaf(xm, cw[gcol*3+0], v);
                v = fmaf(x0, cw[gcol*3+1], v);
                v = fmaf(xp, cw[gcol*3+2], v);
                v = silu_f(v);
                unsigned short hi, lo; split_bf(v, &hi, &lo);
                size_t go = (mBase + l)*512 + gcol;
                xchi[go] = hi; xclo[go] = lo;
            }
        }
        return;
    }

    // per-element epilogues: D[row=(quad*4+r) within 16, col=l16 within 16]
    #pragma unroll
    for (int i = 0; i < 4; ++i) {
        #pragma unroll
        for (int r = 0; r < 4; ++r) {
            size_t row = mBase + wm + 16*i + quad*4 + r;
            #pragma unroll
            for (int j = 0; j < 4; ++j) {
                int col = nBase + wn + 16*j + l16;
                float v = acc[i][j][r] + bias[col];
                if (MODE == 0) {
                    float s = silu_f(v);
                    unsigned short hi, lo; split_bf(s, &hi, &lo);
                    oAhi[row*1024 + 512 + col] = hi;
                    oAlo[row*1024 + 512 + col] = lo;
                } else if (MODE == 1) {
                    outF[row*512 + col] = v;
                } else {
                    size_t aidx = row*512 + col;
                    float xcv = bf2f(Ahi[aidx]) + bf2f(Alo[aidx]);
                    float o = xcv * softplus_f(v);
                    unsigned short hi, lo; split_bf(o, &hi, &lo);
                    oAhi[row*1024 + col] = hi;
                    oAlo[row*1024 + col] = lo;
                }
            }
        }
    }
}

// ---------------- layernorm of (in + resid) per row; emit hi/lo bf16 (in-place over resid) ----------------
__global__ __launch_bounds__(256) void k_ln(const float* __restrict__ in,
    const unsigned short* rhi, const unsigned short* rlo,
    const float* __restrict__ g, const float* __restrict__ b,
    unsigned short* ohi, unsigned short* olo)
{
    int wv = threadIdx.x >> 6, lane = threadIdx.x & 63;
    size_t row = (size_t)blockIdx.x * 4 + wv;
    size_t base = row*512 + lane*8;
    float4 v0 = *(const float4*)(in + base);
    float4 v1 = *(const float4*)(in + base + 4);
    us8 rh = *(const us8*)(rhi + base);
    us8 rl = *(const us8*)(rlo + base);
    float vals[8] = {v0.x,v0.y,v0.z,v0.w,v1.x,v1.y,v1.z,v1.w};
    #pragma unroll
    for (int k = 0; k < 8; ++k) vals[k] += bf2f(rh[k]) + bf2f(rl[k]);
    float s = 0.f, q = 0.f;
    #pragma unroll
    for (int k = 0; k < 8; ++k) { s += vals[k]; q += vals[k]*vals[k]; }
    #pragma unroll
    for (int off = 32; off; off >>= 1) { s += __shfl_xor(s, off); q += __shfl_xor(q, off); }
    float mu = s * (1.0f/512.0f);
    float rs = rsqrtf(q*(1.0f/512.0f) - mu*mu + EPSV);
    const float* gp = g + lane*8;
    const float* bp = b + lane*8;
    float4 g0 = *(const float4*)gp, g1 = *(const float4*)(gp+4);
    float4 b0 = *(const float4*)bp, b1 = *(const float4*)(bp+4);
    float gs[8] = {g0.x,g0.y,g0.z,g0.w,g1.x,g1.y,g1.z,g1.w};
    float bs[8] = {b0.x,b0.y,b0.z,b0.w,b1.x,b1.y,b1.z,b1.w};
    us8 hh, ll;
    #pragma unroll
    for (int k = 0; k < 8; ++k) {
        float o = (vals[k] - mu) * rs * gs[k] + bs[k];
        unsigned short hi, lo; split_bf(o, &hi, &lo);
        hh[k] = hi; ll[k] = lo;
    }
    *(us8*)(ohi + base) = hh;
    *(us8*)(olo + base) = ll;
}

// ---------------- head: reg/dec, gate softmax+argmax, expert select ----------------
__global__ __launch_bounds__(256) void k_head(
    const unsigned short* __restrict__ hhi, const unsigned short* __restrict__ hlo,
    const float* __restrict__ gumbel, const float* __restrict__ gate_w,
    const float* __restrict__ gate_b, const float* __restrict__ actor_w,
    const float* __restrict__ actor_b, const float* __restrict__ critic_w,
    const float* __restrict__ critic_b, float* __restrict__ out, int bofs)
{
    __shared__ float sred[4][4];
    __shared__ float sg;
    __shared__ int sestar;
    int bl = blockIdx.x, tid = threadIdx.x;
    int b = bofs + bl;                     // absolute batch index
    size_t base = (size_t)bl * LL * HD;
    float r0 = 0.f, r1 = 0.f;
    for (int l = 0; l < LL; ++l) {
        size_t o = base + l*HD + tid;
        r0 += bf2f(hhi[o])       + bf2f(hlo[o]);
        r1 += bf2f(hhi[o + 256]) + bf2f(hlo[o + 256]);
    }
    r0 *= (1.0f/LL); r1 *= (1.0f/LL);
    size_t od = base + (LL-1)*HD + tid;
    float dec0 = bf2f(hhi[od])       + bf2f(hlo[od]);
    float dec1 = bf2f(hhi[od + 256]) + bf2f(hlo[od + 256]);

    float p[4];
    #pragma unroll
    for (int e = 0; e < 4; ++e)
        p[e] = r0 * gate_w[tid*4 + e] + r1 * gate_w[(tid+256)*4 + e];
    #pragma unroll
    for (int e = 0; e < 4; ++e) {
        float v = p[e];
        for (int off = 32; off; off >>= 1) v += __shfl_down(v, off);
        p[e] = v;
    }
    int lane = tid & 63, wid = tid >> 6;
    if (!lane) { for (int e = 0; e < 4; ++e) sred[wid][e] = p[e]; }
    __syncthreads();
    if (!tid) {
        float ge[4]; float mx = -1e30f;
        for (int e = 0; e < 4; ++e) {
            ge[e] = sred[0][e]+sred[1][e]+sred[2][e]+sred[3][e] + gate_b[e] + gumbel[b*4 + e];
            if (ge[e] > mx) mx = ge[e];
        }
        float ys[4], den = 0.f;
        for (int e = 0; e < 4; ++e) { ys[e] = expf(ge[e] - mx); den += ys[e]; }
        int estar = 0; float best = ge[0];
        for (int e = 1; e < 4; ++e) if (ge[e] > best) { best = ge[e]; estar = e; }
        float ye = ys[estar] / den;
        float gv = (1.0f + ye) - ye;          // exactly as reference: (hard + y) - y
        for (int e = 0; e < 4; ++e) out[2048 + b*4 + e] = (e == estar) ? gv : 0.0f;
        sg = gv; sestar = estar;
    }
    __syncthreads();
    float gv = sg; int estar = sestar;
    const float* aw  = actor_w  + (size_t)estar * HD * 3;
    const float* cwp = critic_w + (size_t)estar * HD;
    float q[4];
    #pragma unroll
    for (int a = 0; a < 3; ++a)
        q[a] = dec0 * aw[tid*3 + a] + dec1 * aw[(tid+256)*3 + a];
    q[3] = dec0 * cwp[tid] + dec1 * cwp[tid + 256];
    #pragma unroll
    for (int e = 0; e < 4; ++e) {
        float v = q[e];
        for (int off = 32; off; off >>= 1) v += __shfl_down(v, off);
        q[e] = v;
    }
    __syncthreads();
    if (!lane) { for (int e = 0; e < 4; ++e) sred[wid][e] = q[e]; }
    __syncthreads();
    if (!tid) {
        for (int a = 0; a < 3; ++a) {
            float v = sred[0][a]+sred[1][a]+sred[2][a]+sred[3][a];
            out[b*3 + a] = gv * (v + actor_b[estar*3 + a]);
        }
        float v = sred[0][3]+sred[1][3]+sred[2][3]+sred[3][3];
        out[1536 + b] = gv * (v + critic_b[estar]);
    }
}

extern "C" void kernel_launch(void* const* d_in, const int* in_sizes, int n_in,
                              void* d_out, int out_size, void* d_ws, size_t ws_size,
                              hipStream_t stream)
{
    const float* x        = (const float*)d_in[0];
    const float* gumbel   = (const float*)d_in[1];
    const float* w0       = (const float*)d_in[2];
    const float* b0       = (const float*)d_in[3];
    const float* ln_g     = (const float*)d_in[4];
    const float* ln_b     = (const float*)d_in[5];
    const float* gate_w   = (const float*)d_in[6];
    const float* gate_b   = (const float*)d_in[7];
    const float* actor_w  = (const float*)d_in[8];
    const float* actor_b  = (const float*)d_in[9];
    const float* critic_w = (const float*)d_in[10];
    const float* critic_b = (const float*)d_in[11];
    const float* in_w[2]   = {(const float*)d_in[12], (const float*)d_in[22]};
    const float* in_b[2]   = {(const float*)d_in[13], (const float*)d_in[23]};
    const float* conv_w[2] = {(const float*)d_in[14], (const float*)d_in[24]};
    const float* conv_b[2] = {(const float*)d_in[15], (const float*)d_in[25]};
    const float* xp_w[2]   = {(const float*)d_in[16], (const float*)d_in[26]};
    const float* xp_b[2]   = {(const float*)d_in[17], (const float*)d_in[27]};
    const float* dt_w[2]   = {(const float*)d_in[18], (const float*)d_in[28]};
    const float* dt_b[2]   = {(const float*)d_in[19], (const float*)d_in[29]};
    const float* out_w[2]  = {(const float*)d_in[20], (const float*)d_in[30]};
    const float* out_b[2]  = {(const float*)d_in[21], (const float*)d_in[31]};

    // Per-row scratch: union(xb fp32 | xchi+xclo)(2048) + hhi/hlo(2048) + Abig hi/lo(4096) = 8192 B
    int CB = 512;
    while (CB > 1 && (size_t)CB * LL * 8192 + (16u << 20) > ws_size) CB >>= 1;
    const int rows = CB * LL;
    const size_t CSZ = (size_t)rows * HD;        // elements per 512-wide buffer

    char* p = (char*)d_ws;
    float* xb = (float*)p;                       // union with {xchi, xclo}
    unsigned short* xchi = (unsigned short*)p;
    unsigned short* xclo = xchi + CSZ;           p += CSZ * 4;
    unsigned short* hhi = (unsigned short*)p;    p += CSZ * 2;
    unsigned short* hlo = (unsigned short*)p;    p += CSZ * 2;
    unsigned short* Abig_hi = (unsigned short*)p; p += CSZ * 2 * 2;  // rows x 1024 bf16
    unsigned short* Abig_lo = (unsigned short*)p; p += CSZ * 2 * 2;
    unsigned short* wtb = (unsigned short*)p;  p += (size_t)8 * 524288 * 2;
    unsigned short* iwh[2] = {wtb,            wtb + 4*524288};
    unsigned short* iwl[2] = {wtb +   524288, wtb + 5*524288};
    unsigned short* owh[2] = {wtb + 2*524288, wtb + 6*524288};
    unsigned short* owl[2] = {wtb + 3*524288, wtb + 7*524288};
    unsigned short* Uhi[2] = {(unsigned short*)p, (unsigned short*)p + 262144}; p += 262144u * 2 * 2;
    unsigned short* Ulo[2] = {(unsigned short*)p, (unsigned short*)p + 262144}; p += 262144u * 2 * 2;
    float* biasU[2] = {(float*)p, (float*)p + 512};

    // weight transforms: 3 launches
    k_cvt2<<<4096, 256, 0, stream>>>(in_w[0], in_w[1], iwh[0], iwl[0], iwh[1], iwl[1], 1024, 9);
    k_cvt2<<<4096, 256, 0, stream>>>(out_w[0], out_w[1], owh[0], owl[0], owh[1], owl[1], 512, 10);
    k_mkU2<<<2052, 256, 0, stream>>>(xp_w[0], dt_w[0], xp_b[0], dt_b[0],
                                     xp_w[1], dt_w[1], xp_b[1], dt_b[1],
                                     Uhi[0], Ulo[0], Uhi[1], Ulo[1], biasU[0], biasU[1]);

    const int nchunk = BB / CB;
    for (int c = 0; c < nchunk; ++c) {
        const float* xin = x + (size_t)c * CB * LL * FD;
        k_embed<<<rows*HD/256, 256, 0, stream>>>(xin, w0, b0, hhi, hlo);
        for (int m = 0; m < 2; ++m) {
            // in_proj + fused conv: z->Abig[:,512:], conv(xi)->xc hi/lo
            k_mgemm<512, 0><<<dim3(8, rows/128), 256, 0, stream>>>(
                hhi, hlo, iwh[m], iwl[m], in_b[m], conv_w[m], conv_b[m],
                nullptr, Abig_hi, Abig_lo, xchi, xclo);
            // dt GEMM: out = xc * softplus(xc@U + biasU) -> Abig[:,0:512]
            k_mgemm<512, 2><<<dim3(4, rows/128), 256, 0, stream>>>(
                xchi, xclo, Uhi[m], Ulo[m], biasU[m], nullptr, nullptr,
                nullptr, Abig_hi, Abig_lo, nullptr, nullptr);
            // out_proj: Abig @ out_w + out_b -> xb fp32 (residual added in k_ln)
            k_mgemm<1024, 1><<<dim3(4, rows/128), 256, 0, stream>>>(
                Abig_hi, Abig_lo, owh[m], owl[m], out_b[m], nullptr, nullptr,
                xb, nullptr, nullptr, nullptr, nullptr);
            // LN(xb + h_resid) -> hhi/hlo (in-place over resid)
            k_ln<<<rows/4, 256, 0, stream>>>(xb, hhi, hlo, ln_g, ln_b, hhi, hlo);
        }
        k_head<<<CB, 256, 0, stream>>>(hhi, hlo, gumbel, gate_w, gate_b, actor_w, actor_b,
                                       critic_w, critic_b, (float*)d_out, c*CB);
    }
}